// Round 1
// baseline (253.720 us; speedup 1.0000x reference)
//
#include <hip/hip_runtime.h>
#include <stdint.h>

#define M_DIM 8192
#define K_DIM 4096
#define N_DIM 4096
#define BM 128
#define BN 128
#define BK 128

using i32x4 = __attribute__((ext_vector_type(4))) int;

typedef const __attribute__((address_space(1))) void g_void;
typedef __attribute__((address_space(3))) void lds_void;

__device__ __forceinline__ void gload_lds16(const void* g, void* l) {
  // async global->LDS, 16B per lane; LDS dest is wave-uniform base + lane*16
  __builtin_amdgcn_global_load_lds((g_void*)g, (lds_void*)l, 16, 0, 0);
}

__device__ __forceinline__ int sign4(float4 v) {
  int a = (v.x > 0.f) - (v.x < 0.f);
  int b = (v.y > 0.f) - (v.y < 0.f);
  int c = (v.z > 0.f) - (v.z < 0.f);
  int d = (v.w > 0.f) - (v.w < 0.f);
  return (a & 255) | ((b & 255) << 8) | ((c & 255) << 16) | ((d & 255) << 24);
}

// ---- pack x: fp32 [M][K] -> int8 sign [M][K] ----
__global__ void pack_x_kernel(const float* __restrict__ in,
                              int8_t* __restrict__ out, long n) {
  long i0 = ((long)blockIdx.x * blockDim.x + threadIdx.x) * 16;
  long stride = (long)gridDim.x * blockDim.x * 16;
  for (long i = i0; i < n; i += stride) {
    const float4* p = reinterpret_cast<const float4*>(in + i);
    i32x4 r;
    r.x = sign4(p[0]);
    r.y = sign4(p[1]);
    r.z = sign4(p[2]);
    r.w = sign4(p[3]);
    *reinterpret_cast<i32x4*>(out + i) = r;
  }
}

// ---- pack w: fp32 [K][N] -> int8 sign, TRANSPOSED to [N][K] ----
// 64x64 tile via LDS; both global read and global write coalesced.
__global__ void pack_wt_kernel(const float* __restrict__ w,
                               int8_t* __restrict__ wt) {
  __shared__ int8_t tile[64 * 68];  // [n][k], stride 68 breaks bank aliasing
  int n0 = blockIdx.x * 64;
  int k0 = blockIdx.y * 64;
  int t = threadIdx.x;
#pragma unroll
  for (int i = 0; i < 16; ++i) {
    int flat = t + 256 * i;     // 0..4095
    int r = flat >> 6;          // k-local
    int c = flat & 63;          // n-local (consecutive lanes -> coalesced)
    float v = w[(long)(k0 + r) * N_DIM + n0 + c];
    tile[c * 68 + r] = (int8_t)((v > 0.f) - (v < 0.f));
  }
  __syncthreads();
#pragma unroll
  for (int i = 0; i < 4; ++i) {
    int flat = t + 256 * i;     // 1024 * 4B = 4KB tile out
    int nn = flat >> 4;
    int kk = (flat & 15) << 2;
    int word = *reinterpret_cast<const int*>(&tile[nn * 68 + kk]);
    *reinterpret_cast<int*>(wt + (long)(n0 + nn) * K_DIM + k0 + kk) = word;
  }
}

// ---- i8 GEMM: C[M][N] = A[M][K] * B[N][K]^T, m97 128^2 structure ----
// 4 waves (2x2), each wave 64x64 out = 4x4 fragments of 16x16,
// mfma_i32_16x16x64_i8, BK=128 (2 k-substeps per tile).
__global__ __launch_bounds__(256) void gemm_i8_kernel(
    const int8_t* __restrict__ A, const int8_t* __restrict__ B,
    float* __restrict__ C) {
  __shared__ __align__(16) int8_t As[BM * BK];  // 16 KB, linear [128][128]
  __shared__ __align__(16) int8_t Bs[BN * BK];  // 16 KB

  // XCD-aware swizzle: nwg = 64*32 = 2048, divisible by 8 -> bijective
  int bid = blockIdx.x;
  int wg = (bid & 7) * 256 + (bid >> 3);
  int bm = wg >> 5;   // M/BM = 64
  int bn = wg & 31;   // N/BN = 32

  int t = threadIdx.x;
  int wid = t >> 6;
  int lane = t & 63;
  int wr = wid >> 1;
  int wc = wid & 1;

  const int8_t* Abase = A + (long)bm * BM * K_DIM;
  const int8_t* Bbase = B + (long)bn * BN * K_DIM;

  i32x4 acc[4][4];
#pragma unroll
  for (int m = 0; m < 4; ++m)
#pragma unroll
    for (int n = 0; n < 4; ++n)
      acc[m][n] = 0;

  // fragment LDS offsets: row = wave_row*64 + m*16 + (lane&15),
  // k    = ks*64 + (lane>>4)*16  (16 contiguous i8 = ds_read_b128)
  int aoff = (wr * 64 + (lane & 15)) * BK + ((lane >> 4) << 4);
  int boff = (wc * 64 + (lane & 15)) * BK + ((lane >> 4) << 4);

  for (int k0 = 0; k0 < K_DIM; k0 += BK) {
    // stage 16KB A-tile + 16KB B-tile: 4 issues of 16B per thread each
#pragma unroll
    for (int i = 0; i < 4; ++i) {
      int f = i * 256 + t;                       // flat 16B-chunk index
      long g = (long)(f >> 3) * K_DIM + k0 + ((f & 7) << 4);
      int ldsoff = (i * 256 + wid * 64) << 4;    // wave-uniform base
      gload_lds16(Abase + g, As + ldsoff);
      gload_lds16(Bbase + g, Bs + ldsoff);
    }
    __syncthreads();
#pragma unroll
    for (int ks = 0; ks < 2; ++ks) {
      i32x4 af[4], bf[4];
#pragma unroll
      for (int m = 0; m < 4; ++m)
        af[m] = *reinterpret_cast<const i32x4*>(As + aoff + m * 16 * BK + ks * 64);
#pragma unroll
      for (int n = 0; n < 4; ++n)
        bf[n] = *reinterpret_cast<const i32x4*>(Bs + boff + n * 16 * BK + ks * 64);
#pragma unroll
      for (int m = 0; m < 4; ++m)
#pragma unroll
        for (int n = 0; n < 4; ++n)
          acc[m][n] = __builtin_amdgcn_mfma_i32_16x16x64_i8(af[m], bf[n],
                                                            acc[m][n], 0, 0, 0);
    }
    __syncthreads();
  }

  // C/D layout (shape-determined, dtype-independent): col = lane&15,
  // row = (lane>>4)*4 + reg
  long row0 = (long)bm * BM + wr * 64 + ((lane >> 4) << 2);
  long col0 = (long)bn * BN + wc * 64 + (lane & 15);
#pragma unroll
  for (int m = 0; m < 4; ++m)
#pragma unroll
    for (int n = 0; n < 4; ++n)
#pragma unroll
      for (int r = 0; r < 4; ++r)
        C[(row0 + m * 16 + r) * N_DIM + col0 + n * 16] = (float)acc[m][n][r];
}

extern "C" void kernel_launch(void* const* d_in, const int* in_sizes, int n_in,
                              void* d_out, int out_size, void* d_ws, size_t ws_size,
                              hipStream_t stream) {
  const float* x = (const float*)d_in[0];
  const float* w = (const float*)d_in[1];
  float* out = (float*)d_out;

  int8_t* xb = (int8_t*)d_ws;                        // 32 MB: sign(x) [M][K]
  int8_t* wbt = xb + (size_t)M_DIM * K_DIM;          // 16 MB: sign(w)^T [N][K]

  pack_x_kernel<<<2048, 256, 0, stream>>>(x, xb, (long)M_DIM * K_DIM);
  pack_wt_kernel<<<dim3(N_DIM / 64, K_DIM / 64), 256, 0, stream>>>(w, wbt);
  gemm_i8_kernel<<<2048, 256, 0, stream>>>(xb, wbt, out);
}

// Round 2
// 185.181 us; speedup vs baseline: 1.3701x; 1.3701x over previous
//
#include <hip/hip_runtime.h>
#include <stdint.h>

#define M_DIM 8192
#define K_DIM 4096
#define N_DIM 4096

using i32x4 = __attribute__((ext_vector_type(4))) int;

typedef const __attribute__((address_space(1))) void g_void;
typedef __attribute__((address_space(3))) void lds_void;

__device__ __forceinline__ void gload_lds16(const void* g, void* l) {
  // async global->LDS, 16B/lane; LDS dest = wave-uniform base + lane*16
  __builtin_amdgcn_global_load_lds((g_void*)g, (lds_void*)l, 16, 0, 0);
}

__device__ __forceinline__ void barrier_raw() {
  // raw s_barrier (NO vmcnt drain) + compiler-level memory fences so loads
  // cannot hoist/sink across it
  asm volatile("" ::: "memory");
  __builtin_amdgcn_s_barrier();
  asm volatile("" ::: "memory");
}

template <int VM>
__device__ __forceinline__ void wait_vm() {
  if constexpr (VM == 8) asm volatile("s_waitcnt vmcnt(8)" ::: "memory");
  else if constexpr (VM == 4) asm volatile("s_waitcnt vmcnt(4)" ::: "memory");
  else asm volatile("s_waitcnt vmcnt(0)" ::: "memory");
}

__device__ __forceinline__ int sign4(float4 v) {
  int a = (v.x > 0.f) - (v.x < 0.f);
  int b = (v.y > 0.f) - (v.y < 0.f);
  int c = (v.z > 0.f) - (v.z < 0.f);
  int d = (v.w > 0.f) - (v.w < 0.f);
  return (a & 255) | ((b & 255) << 8) | ((c & 255) << 16) | ((d & 255) << 24);
}

// ---- pack x: fp32 [M][K] -> int8 sign [M][K] ----
__global__ void pack_x_kernel(const float* __restrict__ in,
                              int8_t* __restrict__ out, long n) {
  long i0 = ((long)blockIdx.x * blockDim.x + threadIdx.x) * 16;
  long stride = (long)gridDim.x * blockDim.x * 16;
  for (long i = i0; i < n; i += stride) {
    const float4* p = reinterpret_cast<const float4*>(in + i);
    i32x4 r;
    r.x = sign4(p[0]);
    r.y = sign4(p[1]);
    r.z = sign4(p[2]);
    r.w = sign4(p[3]);
    *reinterpret_cast<i32x4*>(out + i) = r;
  }
}

// ---- pack w: fp32 [K][N] -> int8 sign, TRANSPOSED to [N][K] ----
__global__ void pack_wt_kernel(const float* __restrict__ w,
                               int8_t* __restrict__ wt) {
  __shared__ int8_t tile[64 * 68];
  int n0 = blockIdx.x * 64;
  int k0 = blockIdx.y * 64;
  int t = threadIdx.x;
#pragma unroll
  for (int i = 0; i < 16; ++i) {
    int flat = t + 256 * i;
    int r = flat >> 6;          // k-local
    int c = flat & 63;          // n-local (coalesced)
    float v = w[(long)(k0 + r) * N_DIM + n0 + c];
    tile[c * 68 + r] = (int8_t)((v > 0.f) - (v < 0.f));
  }
  __syncthreads();
#pragma unroll
  for (int i = 0; i < 4; ++i) {
    int flat = t + 256 * i;
    int nn = flat >> 4;
    int kk = (flat & 15) << 2;
    int word = *reinterpret_cast<const int*>(&tile[nn * 68 + kk]);
    *reinterpret_cast<int*>(wt + (long)(n0 + nn) * K_DIM + k0 + kk) = word;
  }
}

// ---- i8 GEMM, 256x256 tile, BK=64, 8 waves (2Mx4N), 4-deep LDS pipeline ----
// Per wave: 128x64 output = 8x4 fragments of 16x16, mfma_i32_16x16x64_i8.
// LDS: 4 buffers x (A 16KB + B 16KB) = 128 KiB.
// T2 swizzle: chunk' = chunk ^ ((row>>1)&3)  (rows are 64B = 4 x 16B chunks);
// applied on BOTH the staging global-source and the ds_read address.
template <int VM, bool ISSUE>
__device__ __forceinline__ void tile_step(
    int t, const int8_t* __restrict__ Asrc, const int8_t* __restrict__ Bsrc,
    long aOff0, long aOff1, int dstOff, int8_t* lds, int aRd, int bRd,
    i32x4 (&acc)[8][4]) {
  int8_t* buf = lds + (t & 3) * 32768;
  i32x4 af[4], bf[4];
  // ---- phase 0: frags (m0..3 x n0..3) + prefetch A of tile t+3 ----
#pragma unroll
  for (int m = 0; m < 4; ++m)
    af[m] = *reinterpret_cast<const i32x4*>(buf + aRd + m * 1024);
#pragma unroll
  for (int n = 0; n < 4; ++n)
    bf[n] = *reinterpret_cast<const i32x4*>(buf + bRd + n * 1024);
  if (ISSUE) {
    int kn = (t + 3) * 64;
    int8_t* nbuf = lds + ((t + 3) & 3) * 32768;
    gload_lds16(Asrc + aOff0 + kn, nbuf + dstOff);
    gload_lds16(Asrc + aOff1 + kn, nbuf + 8192 + dstOff);
  }
  barrier_raw();
  asm volatile("s_waitcnt lgkmcnt(0)" ::: "memory");
  __builtin_amdgcn_sched_barrier(0);
  __builtin_amdgcn_s_setprio(1);
#pragma unroll
  for (int m = 0; m < 4; ++m)
#pragma unroll
    for (int n = 0; n < 4; ++n)
      acc[m][n] =
          __builtin_amdgcn_mfma_i32_16x16x64_i8(af[m], bf[n], acc[m][n], 0, 0, 0);
  __builtin_amdgcn_s_setprio(0);
  barrier_raw();
  // ---- phase 1: frags (m4..7 x n0..3, reuse bf) + prefetch B of t+3 ----
#pragma unroll
  for (int m = 0; m < 4; ++m)
    af[m] = *reinterpret_cast<const i32x4*>(buf + aRd + (4 + m) * 1024);
  if (ISSUE) {
    int kn = (t + 3) * 64;
    int8_t* nbuf = lds + ((t + 3) & 3) * 32768;
    gload_lds16(Bsrc + aOff0 + kn, nbuf + 16384 + dstOff);
    gload_lds16(Bsrc + aOff1 + kn, nbuf + 24576 + dstOff);
  }
  barrier_raw();
  asm volatile("s_waitcnt lgkmcnt(0)" ::: "memory");
  __builtin_amdgcn_sched_barrier(0);
  __builtin_amdgcn_s_setprio(1);
#pragma unroll
  for (int m = 0; m < 4; ++m)
#pragma unroll
    for (int n = 0; n < 4; ++n)
      acc[4 + m][n] = __builtin_amdgcn_mfma_i32_16x16x64_i8(af[m], bf[n],
                                                            acc[4 + m][n], 0, 0, 0);
  __builtin_amdgcn_s_setprio(0);
  // gate for next tile: its loads landed (counted, never drain-0 mid-loop)
  wait_vm<VM>();
  barrier_raw();
}

__global__ __launch_bounds__(512, 2) void gemm_i8_kernel(
    const int8_t* __restrict__ A, const int8_t* __restrict__ B,
    float* __restrict__ C) {
  __shared__ __align__(16) int8_t lds[4 * 32768];  // 128 KiB

  // XCD-aware bijective swizzle: nwg = 512 = 8 * 64
  int bid = blockIdx.x;
  int wg = (bid & 7) * 64 + (bid >> 3);
  int bm = wg >> 4;  // M/256 = 32
  int bn = wg & 15;  // N/256 = 16

  int tid = threadIdx.x;
  int wid = tid >> 6;
  int lane = tid & 63;
  int wr = wid >> 2;  // 0..1 (M)
  int wc = wid & 3;   // 0..3 (N)

  const int8_t* Asrc = A + (long)bm * 256 * K_DIM;
  const int8_t* Bsrc = B + (long)bn * 256 * K_DIM;

  // staging: per-issue 512 thr x 16B = 8KB = 128 rows of 64B.
  // dst (linear): row = j*128 + (tid>>2), chunk = tid&3
  // src holds global chunk (tid&3) ^ ((row>>1)&3); (row>>1)&3 == (tid>>3)&3
  int srcChunk = ((tid & 3) ^ ((tid >> 3) & 3)) << 4;
  long aOff0 = (long)(tid >> 2) * K_DIM + srcChunk;
  long aOff1 = (long)(128 + (tid >> 2)) * K_DIM + srcChunk;
  int dstOff = wid * 1024;  // wave-uniform; HW adds lane*16

  // ds_read bases: row = w*Wstride + m*16 + (lane&15), logical chunk = lane>>4,
  // swizzled chunk' = (lane>>4) ^ (((lane&15)>>1)&3)  (m,wr,wc drop out mod 4)
  int rswz = ((lane >> 4) ^ (((lane & 15) >> 1) & 3)) << 4;
  int aRd = (wr * 128 + (lane & 15)) * 64 + rswz;
  int bRd = 16384 + (wc * 64 + (lane & 15)) * 64 + rswz;

  i32x4 acc[8][4] = {};

  // prologue: stage tiles 0,1,2 (12 loads/wave in flight)
#pragma unroll
  for (int t = 0; t < 3; ++t) {
    int8_t* buf = lds + t * 32768;
    int k0 = t * 64;
    gload_lds16(Asrc + aOff0 + k0, buf + dstOff);
    gload_lds16(Asrc + aOff1 + k0, buf + 8192 + dstOff);
    gload_lds16(Bsrc + aOff0 + k0, buf + 16384 + dstOff);
    gload_lds16(Bsrc + aOff1 + k0, buf + 24576 + dstOff);
  }
  wait_vm<8>();  // tile 0 landed; tiles 1,2 in flight
  barrier_raw();

#pragma unroll 1
  for (int t = 0; t < 61; ++t)
    tile_step<8, true>(t, Asrc, Bsrc, aOff0, aOff1, dstOff, lds, aRd, bRd, acc);
  tile_step<4, false>(61, Asrc, Bsrc, aOff0, aOff1, dstOff, lds, aRd, bRd, acc);
  tile_step<0, false>(62, Asrc, Bsrc, aOff0, aOff1, dstOff, lds, aRd, bRd, acc);
  tile_step<0, false>(63, Asrc, Bsrc, aOff0, aOff1, dstOff, lds, aRd, bRd, acc);

  // C/D layout: col = lane&15, row = (lane>>4)*4 + reg
  long row0 = (long)bm * 256 + wr * 128 + ((lane >> 4) << 2);
  long col0 = (long)bn * 256 + wc * 64 + (lane & 15);
#pragma unroll
  for (int m = 0; m < 8; ++m)
#pragma unroll
    for (int n = 0; n < 4; ++n)
#pragma unroll
      for (int r = 0; r < 4; ++r)
        C[(row0 + m * 16 + r) * N_DIM + col0 + n * 16] = (float)acc[m][n][r];
}

extern "C" void kernel_launch(void* const* d_in, const int* in_sizes, int n_in,
                              void* d_out, int out_size, void* d_ws, size_t ws_size,
                              hipStream_t stream) {
  const float* x = (const float*)d_in[0];
  const float* w = (const float*)d_in[1];
  float* out = (float*)d_out;

  int8_t* xb = (int8_t*)d_ws;                // 32 MB: sign(x) [M][K]
  int8_t* wbt = xb + (size_t)M_DIM * K_DIM;  // 16 MB: sign(w)^T [N][K]

  pack_x_kernel<<<2048, 256, 0, stream>>>(x, xb, (long)M_DIM * K_DIM);
  pack_wt_kernel<<<dim3(N_DIM / 64, K_DIM / 64), 256, 0, stream>>>(w, wbt);
  gemm_i8_kernel<<<512, 512, 0, stream>>>(xb, wbt, out);
}